// Round 12
// baseline (1018.584 us; speedup 1.0000x reference)
//
#include <hip/hip_runtime.h>
#include <math.h>

namespace {
constexpr int BN = 64;
constexpr int HW = 1024;
constexpr int NS = BN*8*HW;      // 524288
constexpr int NT = 1024;         // 2-row tiles

constexpr float C2f = 0.2f, C3f = 0.3f, C4f = 0.8f, C5f = (float)(8.0/9.0);
constexpr float A21 = 0.2f;
constexpr float A31 = (float)(3.0/40.0),  A32 = (float)(9.0/40.0);
constexpr float A41 = (float)(44.0/45.0), A42 = (float)(-56.0/15.0), A43 = (float)(32.0/9.0);
constexpr float A51 = (float)(19372.0/6561.0), A52 = (float)(-25360.0/2187.0),
                A53 = (float)(64448.0/6561.0), A54 = (float)(-212.0/729.0);
constexpr float A61 = (float)(9017.0/3168.0), A62 = (float)(-355.0/33.0),
                A63 = (float)(46732.0/5247.0), A64 = (float)(49.0/176.0),
                A65 = (float)(-5103.0/18656.0);
constexpr float B1c = (float)(35.0/384.0), B3c = (float)(500.0/1113.0),
                B4c = (float)(125.0/192.0), B5c = (float)(-2187.0/6784.0),
                B6c = (float)(11.0/84.0);
constexpr float E1c = (float)(71.0/57600.0), E3c = (float)(-71.0/16695.0),
                E4c = (float)(71.0/1920.0), E5c = (float)(-17253.0/339200.0),
                E6c = (float)(22.0/525.0),  E7c = (float)(-1.0/40.0);
constexpr float RTOL = 1e-3f, ATOL = 1e-3f;

// ws layout (floats / ints)
constexpr size_t OFF_PART = 0;        // 2048 floats (2 parities x 1024 tiles)
constexpr size_t OFF_FLAG = 2048;     // 1024 ints
constexpr size_t OFF_CNT  = 3072;     // 1 int (+pad)
constexpr size_t OFF_TSUM = 3136;     // 576
constexpr size_t OFF_W2P  = 3712;     // 73728 ushorts = 36864 floats
constexpr size_t OFF_Y    = 40576;    // y buffers px-major: [b][px][8]
constexpr size_t OFF_Y5   = OFF_Y  + (size_t)NS;
constexpr size_t OFF_K    = OFF_Y5 + (size_t)NS;   // 7*NS (k1..k7, px-major)
}

__constant__ float g_cf[6][5] = {
    {A21, 0, 0, 0, 0},
    {A31, A32, 0, 0, 0},
    {A41, A42, A43, 0, 0},
    {A51, A52, A53, A54, 0},
    {A61, A62, A63, A64, A65},
    {0, 0, 0, 0, 0}};
__constant__ float g_ct[6] = {C2f, C3f, C4f, C5f, 1.0f, 1.0f};

typedef __bf16 bfrag8 __attribute__((ext_vector_type(8)));
typedef float f32x16 __attribute__((ext_vector_type(16)));

__device__ __forceinline__ unsigned short f2bf(float f) {
    unsigned u = __float_as_uint(f);
    unsigned r = u + 0x7fffu + ((u >> 16) & 1u);
    return (unsigned short)(r >> 16);
}
__device__ __forceinline__ float bf2f(unsigned short h) {
    return __uint_as_float(((unsigned)h) << 16);
}

// ---- system-scope (L3-coherent) accessors ----
__device__ __forceinline__ float ld_sysf(const float* p) {
    return __hip_atomic_load(p, __ATOMIC_RELAXED, __HIP_MEMORY_SCOPE_SYSTEM);
}
__device__ __forceinline__ float2 ld_sysf2(const float* p) {
    union { unsigned long long u; float2 f; } c;
    c.u = __hip_atomic_load((const unsigned long long*)p, __ATOMIC_RELAXED,
                            __HIP_MEMORY_SCOPE_SYSTEM);
    return c.f;
}
__device__ __forceinline__ void st_sysf(float* p, float v) {
    __hip_atomic_store(p, v, __ATOMIC_RELAXED, __HIP_MEMORY_SCOPE_SYSTEM);
}
__device__ __forceinline__ void st_sysf2(float* p, float a, float b) {
    union { unsigned long long u; float2 f; } c;
    c.f = make_float2(a, b);
    __hip_atomic_store((unsigned long long*)p, c.u, __ATOMIC_RELAXED,
                       __HIP_MEMORY_SCOPE_SYSTEM);
}
__device__ __forceinline__ void ld8s(const float* p, float* v) {
    #pragma unroll
    for (int h = 0; h < 4; h++) {
        float2 t = ld_sysf2(p + 2*h);
        v[2*h] = t.x; v[2*h+1] = t.y;
    }
}
__device__ __forceinline__ void st8s(float* p, const float* v) {
    st_sysf2(p,     v[0], v[1]);
    st_sysf2(p + 2, v[2], v[3]);
    st_sysf2(p + 4, v[4], v[5]);
    st_sysf2(p + 6, v[6], v[7]);
}

// ---------------- init: y0 (px-major) = concat(x, zeros); zero sync state ----------------
__global__ __launch_bounds__(256)
void k_init(const float* __restrict__ x, float* __restrict__ y,
            int* __restrict__ flags, unsigned* __restrict__ cnt)
{
    int idx = blockIdx.x*256 + threadIdx.x;           // < NS
    int b = idx >> 13, px = (idx >> 3) & 1023, c = idx & 7;
    y[idx] = (c < 3) ? x[(size_t)(b*3 + c)*1024 + px] : 0.0f;
    if (idx < NT) flags[idx] = 0;
    if (idx == 1200) *cnt = 0u;
}

// ---------------- prepack w2 into 32x32x16 B-frag order + t-channel mask table ----------------
// flat frag index: (((part*9 + tap)*4 + ks)*2 + nt)*512 + lane*8 + j
// lane: oc = nt*32 + (lane&31), k: ic = ks*16 + (lane>>5)*8 + j
__global__ __launch_bounds__(256)
void k_prepack(const float* __restrict__ w2, unsigned short* __restrict__ w2p,
               float* __restrict__ tsum)
{
    int gid = blockIdx.x*256 + threadIdx.x;
    if (gid < 73728) {
        int j    = gid & 7;
        int lane = (gid >> 3) & 63;
        int nt   = (gid >> 9) & 1;
        int ks   = (gid >> 10) & 3;
        int r    = gid >> 12;            // part*9 + tap
        int tap  = r % 9;
        int part = r / 9;
        int oc = nt*32 + (lane & 31);
        int ic = ks*16 + (lane >> 5)*8 + j;
        float wv = w2[oc*585 + (1 + ic)*9 + tap];
        unsigned short hi = f2bf(wv);
        w2p[gid] = (part == 0) ? hi : f2bf(wv - bf2f(hi));
    }
    if (gid < 576) {
        int oc = gid & 63, combo = gid >> 6;       // 0..8
        int rcase = combo / 3, ccase = combo % 3;
        float s = 0.0f;
        for (int kh = 0; kh < 3; kh++) {
            if ((rcase == 1 && kh == 0) || (rcase == 2 && kh == 2)) continue;
            for (int kw = 0; kw < 3; kw++) {
                if ((ccase == 1 && kw == 0) || (ccase == 2 && kw == 2)) continue;
                s += w2[oc*585 + kh*3 + kw];
            }
        }
        tsum[gid] = s;
    }
}

// ---------------- the whole ODE solve: one co-resident kernel ----------------
// 2-row tiles (1024), static LDS ~45 KB -> 3 blocks/CU for phase overlap.
// All k/y I/O system-scope (L3-coherent); per-tile flags for halo deps;
// one counter rendezvous per step. Plain (non-cooperative) launch, grid
// capped at occupancy capacity.
__global__ void __launch_bounds__(256, 3)
k_ode(const float* __restrict__ w1, const float* __restrict__ b1,
      const float* __restrict__ b2, const float* __restrict__ w3,
      const float* __restrict__ b3, const unsigned short* __restrict__ w2p,
      const float* __restrict__ tsumg, const float* __restrict__ wl,
      const float* __restrict__ bl, float* __restrict__ ybuf,
      float* __restrict__ y5buf, float* __restrict__ kb,
      float* __restrict__ part, int* __restrict__ flags,
      unsigned* __restrict__ cnt, float* __restrict__ out)
{
    // pool: 4 rows x 34 px x 272 B = 36992 (conv1 out / conv2 in; h2+c3part overlay)
    __shared__ __align__(16) unsigned char s_pool[36992];
    __shared__ __align__(16) float s_w1t[8][64];
    __shared__ float s_w10[64], s_b1v[64];
    __shared__ __align__(16) float s_w3t[64][8];
    __shared__ float s_w30[8], s_b3v[8];
    __shared__ float s_tsum[576];
    __shared__ float s_b2v[64];
    __shared__ float s_red[256];

    const int tid = threadIdx.x;
    const int nblk = gridDim.x;
    const int lane = tid & 63;
    const int m32 = lane & 31, q2 = lane >> 5;
    const int wvid = tid >> 6;
    const int rp = wvid >> 1;         // output row of 2-row tile
    const int np = wvid & 1;          // oc-half

    if (tid < 64) {
        s_b1v[tid] = b1[tid];
        s_w10[tid] = w1[tid*9];
        #pragma unroll
        for (int c = 0; c < 8; c++) s_w1t[c][tid] = w1[tid*9 + 1 + c];
        s_b2v[tid] = b2[tid];
        #pragma unroll
        for (int o = 0; o < 8; o++) s_w3t[tid][o] = w3[o*65 + 1 + tid];
        if (tid < 8) { s_w30[tid] = w3[tid*65]; s_b3v[tid] = b3[tid]; }
    }
    for (int i = tid; i < 576; i += 256) s_tsum[i] = tsumg[i];

    float t = 0.0f, dt = 0.1f;
    float* ya = ybuf; float* yb = y5buf;
    float* ka = kb;  float* kg = kb + 6*(size_t)NS;
    unsigned rnd = 0;

    auto rendezvous = [&]() {
        rnd++;
        __syncthreads();
        if (tid == 0) {
            __hip_atomic_fetch_add(cnt, 1u, __ATOMIC_RELAXED, __HIP_MEMORY_SCOPE_SYSTEM);
            unsigned target = (unsigned)nblk * rnd;
            while (__hip_atomic_load(cnt, __ATOMIC_RELAXED,
                                     __HIP_MEMORY_SCOPE_SYSTEM) < target)
                __builtin_amdgcn_s_sleep(2);
        }
        __syncthreads();
    };

    auto eval = [&](const float* src, int nc, const float* cf, float ctv,
                    float* kout, int mode, int gev, float* partp) {
        float dtc = fminf(dt, 1.0f - t);
        float ts  = t + ctv*dtc;

        for (int tile = blockIdx.x; tile < NT; tile += nblk) {
            int b = tile >> 4, rg = tile & 15;

            // 1) zero halo columns (cols 0 & 33, 4 rows = 8 px); tid0 spins on flags
            if (tid < 128) {
                int px_id = tid >> 4, u = tid & 15;
                int row = px_id >> 1, colh = (px_id & 1) ? 33 : 0;
                *(uint4*)(s_pool + (size_t)(row*34 + colh)*272 + u*16) =
                    make_uint4(0u,0u,0u,0u);
            }
            if (tid == 0 && gev > 1) {
                if (rg > 0)
                    while (__hip_atomic_load(&flags[tile-1], __ATOMIC_RELAXED,
                                             __HIP_MEMORY_SCOPE_SYSTEM) < gev-1)
                        __builtin_amdgcn_s_sleep(1);
                if (rg < 15)
                    while (__hip_atomic_load(&flags[tile+1], __ATOMIC_RELAXED,
                                             __HIP_MEMORY_SCOPE_SYSTEM) < gev-1)
                        __builtin_amdgcn_s_sleep(1);
            }
            __syncthreads();

            // 2) conv1 (z-combine + 1x1 9->64 + relu) into LDS, 4 rows incl halo
            if (tid < 128) {
                int lr = tid >> 5, col = tid & 31;
                int r = rg*2 - 1 + lr;
                int pxi = lr*34 + col + 1;
                uint4* d = (uint4*)(s_pool + (size_t)pxi*272);
                if ((unsigned)r < 32u) {
                    int px = (r << 5) + col;
                    size_t pb8 = ((size_t)(b << 10) + px) << 3;
                    float s[8] = {0,0,0,0,0,0,0,0};
                    for (int j = 0; j < nc; j++) {
                        const float* kp = (j == 0 ? ka : kb + (size_t)j*NS) + pb8;
                        float a = cf[j];
                        float kv[8];
                        ld8s(kp, kv);
                        #pragma unroll
                        for (int c = 0; c < 8; c++) s[c] += a*kv[c];
                    }
                    float zz[8];
                    {
                        float sv[8];
                        ld8s(src + pb8, sv);
                        #pragma unroll
                        for (int c = 0; c < 8; c++) zz[c] = sv[c] + dtc*s[c];
                    }
                    float acc[64];
                    #pragma unroll
                    for (int o = 0; o < 64; o++) acc[o] = fmaf(ts, s_w10[o], s_b1v[o]);
                    #pragma unroll
                    for (int c = 0; c < 8; c++) {
                        float zc = zz[c];
                        const float4* w4 = reinterpret_cast<const float4*>(&s_w1t[c][0]);
                        #pragma unroll
                        for (int qq = 0; qq < 16; qq++) {
                            float4 wq = w4[qq];
                            acc[4*qq+0] = fmaf(wq.x, zc, acc[4*qq+0]);
                            acc[4*qq+1] = fmaf(wq.y, zc, acc[4*qq+1]);
                            acc[4*qq+2] = fmaf(wq.z, zc, acc[4*qq+2]);
                            acc[4*qq+3] = fmaf(wq.w, zc, acc[4*qq+3]);
                        }
                    }
                    unsigned hibuf[32], lobuf[32];
                    #pragma unroll
                    for (int i = 0; i < 32; i++) {
                        float f0 = fmaxf(acc[2*i],   0.0f);
                        float f1 = fmaxf(acc[2*i+1], 0.0f);
                        unsigned short h0 = f2bf(f0), h1v = f2bf(f1);
                        unsigned short l0 = f2bf(f0 - bf2f(h0)), l1 = f2bf(f1 - bf2f(h1v));
                        hibuf[i] = (unsigned)h0 | ((unsigned)h1v << 16);
                        lobuf[i] = (unsigned)l0 | ((unsigned)l1 << 16);
                    }
                    const uint4* hbv = (const uint4*)hibuf;
                    const uint4* lbv = (const uint4*)lobuf;
                    #pragma unroll
                    for (int i = 0; i < 8; i++) d[i] = hbv[i];
                    #pragma unroll
                    for (int i = 0; i < 8; i++) d[8 + i] = lbv[i];
                } else {
                    uint4 z4 = make_uint4(0u,0u,0u,0u);
                    #pragma unroll
                    for (int i = 0; i < 16; i++) d[i] = z4;
                }
            }
            __syncthreads();

            // 3) conv2: 3x3 65->64 split-bf16 via 32x32x16 MFMA
            //    wave (rp,np) -> output row rp, oc-half np (1 C-tile)
            f32x16 acc2 = (f32x16)(0.0f);
            const size_t partOff = (size_t)9*4*2*512;   // lo-part offset = 36864
            for (int cc = 0; cc < 2; cc++) {
                #pragma unroll 1
                for (int kh = 0; kh < 3; kh++) {
                    int lr = rp + kh;
                    #pragma unroll
                    for (int kw = 0; kw < 3; kw++) {
                        int tap = kh*3 + kw;
                        #pragma unroll
                        for (int s = 0; s < 2; s++) {
                            int ks = cc*2 + s;
                            int aoff = cc*64 + s*32 + q2*16;
                            const unsigned char* pxp = s_pool
                                + (size_t)(lr*34 + m32 + kw)*272 + aoff;
                            bfrag8 ah = *(const bfrag8*)pxp;
                            bfrag8 al = *(const bfrag8*)(pxp + 128);
                            const unsigned short* bbase =
                                w2p + (size_t)((tap*4 + ks)*2 + np)*512 + lane*8;
                            bfrag8 bh = *(const bfrag8*)bbase;
                            bfrag8 bl = *(const bfrag8*)(bbase + partOff);
                            acc2 = __builtin_amdgcn_mfma_f32_32x32x16_bf16(
                                ah, bh, acc2, 0, 0, 0);
                            acc2 = __builtin_amdgcn_mfma_f32_32x32x16_bf16(
                                ah, bl, acc2, 0, 0, 0);
                            acc2 = __builtin_amdgcn_mfma_f32_32x32x16_bf16(
                                al, bh, acc2, 0, 0, 0);
                        }
                    }
                }
            }
            __syncthreads();   // before h2 overlay on pool

            // 4) epilogue: t-channel + bias + relu -> LDS h2 [64 oc][64 px] stride 65
            // C/D: oc-col = lane&31, px-col = (reg&3)+8*(reg>>2)+4*q2, row = rp
            {
                float* s_h2 = (float*)s_pool;
                int r_out = rg*2 + rp;
                int rcase = (r_out == 0) ? 1 : ((r_out == 31) ? 2 : 0);
                int oc = np*32 + m32;
                float tb = s_b2v[oc];
                #pragma unroll
                for (int reg = 0; reg < 16; reg++) {
                    int cpos = (reg & 3) + 8*(reg >> 2) + 4*q2;
                    int ccase = (cpos == 0) ? 1 : ((cpos == 31) ? 2 : 0);
                    float tsv = s_tsum[(rcase*3 + ccase)*64 + oc];
                    s_h2[oc*65 + rp*32 + cpos] =
                        fmaxf(acc2[reg] + ts*tsv + tb, 0.0f);
                }
            }
            __syncthreads();

            // 5a) conv3 partials: 128 threads, px = tid&63, c-half = tid>>6
            if (tid < 128) {
                const float* s_h2 = (const float*)s_pool;
                int px = tid & 63, hf = tid >> 6;
                float a3[8];
                #pragma unroll
                for (int o = 0; o < 8; o++)
                    a3[o] = hf ? 0.0f : fmaf(ts, s_w30[o], s_b3v[o]);
                #pragma unroll 8
                for (int c32 = 0; c32 < 32; c32++) {
                    int c = hf*32 + c32;
                    float xv = s_h2[c*65 + px];
                    const float4* w4 = (const float4*)&s_w3t[c][0];
                    float4 wA = w4[0], wB = w4[1];
                    a3[0] = fmaf(wA.x, xv, a3[0]);
                    a3[1] = fmaf(wA.y, xv, a3[1]);
                    a3[2] = fmaf(wA.z, xv, a3[2]);
                    a3[3] = fmaf(wA.w, xv, a3[3]);
                    a3[4] = fmaf(wB.x, xv, a3[4]);
                    a3[5] = fmaf(wB.y, xv, a3[5]);
                    a3[6] = fmaf(wB.z, xv, a3[6]);
                    a3[7] = fmaf(wB.w, xv, a3[7]);
                }
                float* cp = (float*)(s_pool + 16640) + (size_t)(hf*64 + px)*8;
                *(float4*)cp       = make_float4(a3[0], a3[1], a3[2], a3[3]);
                *(float4*)(cp + 4) = make_float4(a3[4], a3[5], a3[6], a3[7]);
            }
            __syncthreads();

            // 5b) finalize: 64 threads combine halves + mode epilogues (sys I/O)
            if (tid < 64) {
                const float* cp = (float*)(s_pool + 16640);
                float a3[8];
                #pragma unroll
                for (int o = 0; o < 8; o++)
                    a3[o] = cp[(size_t)tid*8 + o] + cp[(size_t)(64 + tid)*8 + o];
                int px = rg*64 + tid;
                size_t pb8 = ((size_t)(b << 10) + px) << 3;
                st8s(kout + pb8, a3);
                if (mode == 1) {
                    float kv1[8], kv3[8], kv4[8], kv5[8], yv[8], r8[8];
                    ld8s(ka + pb8, kv1);
                    ld8s(kb + 2*(size_t)NS + pb8, kv3);
                    ld8s(kb + 3*(size_t)NS + pb8, kv4);
                    ld8s(kb + 4*(size_t)NS + pb8, kv5);
                    ld8s(ya + pb8, yv);
                    #pragma unroll
                    for (int c = 0; c < 8; c++)
                        r8[c] = yv[c] + dtc*(B1c*kv1[c] + B3c*kv3[c] + B4c*kv4[c]
                                             + B5c*kv5[c] + B6c*a3[c]);
                    st8s(yb + pb8, r8);
                } else if (mode == 2) {
                    float kv1[8], kv3[8], kv4[8], kv5[8], kv6[8], yv[8], y5v[8];
                    ld8s(ka + pb8, kv1);
                    ld8s(kb + 2*(size_t)NS + pb8, kv3);
                    ld8s(kb + 3*(size_t)NS + pb8, kv4);
                    ld8s(kb + 4*(size_t)NS + pb8, kv5);
                    ld8s(kb + 5*(size_t)NS + pb8, kv6);
                    ld8s(ya + pb8, yv);
                    ld8s(yb + pb8, y5v);
                    float ls = 0.0f;
                    #pragma unroll
                    for (int c = 0; c < 8; c++) {
                        float e = dtc*(E1c*kv1[c] + E3c*kv3[c] + E4c*kv4[c]
                                       + E5c*kv5[c] + E6c*kv6[c] + E7c*a3[c]);
                        float tol = ATOL + RTOL*fmaxf(fabsf(yv[c]), fabsf(y5v[c]));
                        float rr = e / tol;
                        ls += rr*rr;
                    }
                    s_red[tid] = ls;
                }
            }
            if (mode == 2) {
                if (tid >= 64) s_red[tid] = 0.0f;
                __syncthreads();
                for (int sft = 128; sft > 0; sft >>= 1) {
                    if (tid < sft) s_red[tid] += s_red[tid + sft];
                    __syncthreads();
                }
                if (tid == 0) st_sysf(&partp[tile], s_red[0]);
            }
            // release: syncthreads drains vmcnt (sys stores at L3), then flag
            __syncthreads();
            if (tid == 0)
                __hip_atomic_store(&flags[tile], gev, __ATOMIC_RELAXED,
                                   __HIP_MEMORY_SCOPE_SYSTEM);
        }
    };

    int gev = 1;
    eval(ya, 0, g_cf[5], 0.0f, ka, 0, gev, part);   // k1 = f(t0, y0)
    gev++;

    for (int st = 0; st < 24; st++) {
        if (t >= 1.0f - 1e-7f) break;
        float* partp = part + (size_t)(st & 1)*NT;
        for (int e = 0; e < 6; e++) {
            int nc = (e < 5) ? e + 1 : 0;
            const float* src = (e == 5) ? yb : ya;
            float* kout = (e < 5) ? kb + (size_t)(e + 1)*NS : kg;
            int mode = (e == 4) ? 1 : ((e == 5) ? 2 : 0);
            eval(src, nc, g_cf[e], g_ct[e], kout, mode, gev, partp);
            gev++;
        }
        rendezvous();   // all partials (sys) visible
        float v = ld_sysf(&partp[tid]) + ld_sysf(&partp[tid + 256])
                + ld_sysf(&partp[tid + 512]) + ld_sysf(&partp[tid + 768]);
        s_red[tid] = v;
        __syncthreads();
        for (int sft = 128; sft > 0; sft >>= 1) {
            if (tid < sft) s_red[tid] += s_red[tid + sft];
            __syncthreads();
        }
        float red0 = s_red[0];
        __syncthreads();
        float err_norm = sqrtf(red0 / (float)NS);
        float dtc = fminf(dt, 1.0f - t);
        bool adv = (err_norm <= 1.0f);
        if (adv) {
            t = t + dtc;
            float* tmp = ya; ya = yb; yb = tmp;   // y <- y5
            tmp = ka; ka = kg; kg = tmp;          // k1 <- k7 (FSAL)
        }
        float safe = fmaxf(err_norm, 1e-10f);
        float factor = fminf(fmaxf(0.9f*powf(safe, -0.2f), 0.2f), 10.0f);
        dt = dtc*factor;
    }

    // all y writes were system-scope; one rendezvous then the head
    rendezvous();

    // final linear head: y is px-major [b][px][8]; wl flat index = c*1024+px
    for (int bh = blockIdx.x; bh < 64; bh += nblk) {
        float* s_hred = (float*)s_pool;   // 10*256 floats overlay
        float acc[10];
        #pragma unroll
        for (int m = 0; m < 10; m++) acc[m] = 0.0f;
        for (int px = tid; px < 1024; px += 256) {
            const float* yp = ya + (((size_t)(bh << 10) + px) << 3);
            float yv[8];
            #pragma unroll
            for (int h = 0; h < 4; h++) {
                float2 v = ld_sysf2(yp + 2*h);
                yv[2*h] = v.x; yv[2*h+1] = v.y;
            }
            #pragma unroll
            for (int c = 0; c < 8; c++) {
                float v = yv[c];
                #pragma unroll
                for (int m = 0; m < 10; m++)
                    acc[m] = fmaf(v, wl[(size_t)m*8192 + (c << 10) + px], acc[m]);
            }
        }
        #pragma unroll
        for (int m = 0; m < 10; m++) s_hred[m*256 + tid] = acc[m];
        __syncthreads();
        for (int sft = 128; sft > 0; sft >>= 1) {
            if (tid < sft) {
                #pragma unroll
                for (int m = 0; m < 10; m++)
                    s_hred[m*256 + tid] += s_hred[m*256 + tid + sft];
            }
            __syncthreads();
        }
        if (tid < 10) out[bh*10 + tid] = s_hred[tid*256] + bl[tid];
        __syncthreads();
    }
}

// ---------------- host ----------------
extern "C" void kernel_launch(void* const* d_in, const int* in_sizes, int n_in,
                              void* d_out, int out_size, void* d_ws, size_t ws_size,
                              hipStream_t stream)
{
    const float* x  = (const float*)d_in[0];
    const float* w1 = (const float*)d_in[1];
    const float* b1 = (const float*)d_in[2];
    const float* w2 = (const float*)d_in[3];
    const float* b2 = (const float*)d_in[4];
    const float* w3 = (const float*)d_in[5];
    const float* b3 = (const float*)d_in[6];
    const float* wl = (const float*)d_in[7];
    const float* bl = (const float*)d_in[8];
    float* out = (float*)d_out;

    float* F = (float*)d_ws;
    float* part = F + OFF_PART;
    int*   flags = (int*)(F + OFF_FLAG);
    unsigned* cnt = (unsigned*)(F + OFF_CNT);
    float* tsum = F + OFF_TSUM;
    unsigned short* w2p = (unsigned short*)(F + OFF_W2P);
    float* y    = F + OFF_Y;
    float* y5   = F + OFF_Y5;
    float* kbp  = F + OFF_K;

    k_init<<<NS/256, 256, 0, stream>>>(x, y, flags, cnt);
    k_prepack<<<288, 256, 0, stream>>>(w2, w2p, tsum);

    // plain launch; grid capped at guaranteed co-resident capacity
    int maxb = 0;
    if (hipOccupancyMaxActiveBlocksPerMultiprocessor(&maxb,
            reinterpret_cast<const void*>(k_ode), 256, 0) != hipSuccess || maxb < 1)
        maxb = 1;
    int cus = 256;
    {
        int dev = 0;
        hipGetDevice(&dev);
        hipDeviceProp_t prop;
        if (hipGetDeviceProperties(&prop, dev) == hipSuccess && prop.multiProcessorCount > 0)
            cus = prop.multiProcessorCount;
    }
    long cap = (long)maxb * (long)cus;
    int gridn = (int)((cap < NT) ? cap : NT);
    if (gridn < 16) gridn = 16;

    k_ode<<<gridn, 256, 0, stream>>>(w1, b1, b2, w3, b3, w2p, tsum, wl, bl,
                                     y, y5, kbp, part, flags, cnt, out);
}

// Round 13
// 630.554 us; speedup vs baseline: 1.6154x; 1.6154x over previous
//
#include <hip/hip_runtime.h>
#include <math.h>

namespace {
constexpr int BN = 64;
constexpr int HW = 1024;
constexpr int NS = BN*8*HW;      // 524288

constexpr float C2f = 0.2f, C3f = 0.3f, C4f = 0.8f, C5f = (float)(8.0/9.0);
constexpr float A21 = 0.2f;
constexpr float A31 = (float)(3.0/40.0),  A32 = (float)(9.0/40.0);
constexpr float A41 = (float)(44.0/45.0), A42 = (float)(-56.0/15.0), A43 = (float)(32.0/9.0);
constexpr float A51 = (float)(19372.0/6561.0), A52 = (float)(-25360.0/2187.0),
                A53 = (float)(64448.0/6561.0), A54 = (float)(-212.0/729.0);
constexpr float A61 = (float)(9017.0/3168.0), A62 = (float)(-355.0/33.0),
                A63 = (float)(46732.0/5247.0), A64 = (float)(49.0/176.0),
                A65 = (float)(-5103.0/18656.0);
constexpr float B1c = (float)(35.0/384.0), B3c = (float)(500.0/1113.0),
                B4c = (float)(125.0/192.0), B5c = (float)(-2187.0/6784.0),
                B6c = (float)(11.0/84.0);
constexpr float E1c = (float)(71.0/57600.0), E3c = (float)(-71.0/16695.0),
                E4c = (float)(71.0/1920.0), E5c = (float)(-17253.0/339200.0),
                E6c = (float)(22.0/525.0),  E7c = (float)(-1.0/40.0);
constexpr float RTOL = 1e-3f, ATOL = 1e-3f;

// ws layout (floats / ints)
constexpr size_t OFF_PART = 0;        // 1024 floats (double-buffered by step parity)
constexpr size_t OFF_FLAG = 1024;     // 512 ints
constexpr size_t OFF_CNT  = 1536;     // 1 int (+pad)
constexpr size_t OFF_TSUM = 1600;     // 576
constexpr size_t OFF_W2P  = 2176;     // 36864 halfs = 18432 floats
constexpr size_t OFF_Y    = 20608;    // y buffers px-major: [b][px][8]
constexpr size_t OFF_Y5   = OFF_Y  + (size_t)NS;
constexpr size_t OFF_K    = OFF_Y5 + (size_t)NS;   // 7*NS (k1..k7, px-major)
}

__constant__ float g_cf[6][5] = {
    {A21, 0, 0, 0, 0},
    {A31, A32, 0, 0, 0},
    {A41, A42, A43, 0, 0},
    {A51, A52, A53, A54, 0},
    {A61, A62, A63, A64, A65},
    {0, 0, 0, 0, 0}};
__constant__ float g_ct[6] = {C2f, C3f, C4f, C5f, 1.0f, 1.0f};

typedef _Float16 hfrag8 __attribute__((ext_vector_type(8)));
typedef float f32x16 __attribute__((ext_vector_type(16)));

// ---- system-scope (L3-coherent) accessors ----
__device__ __forceinline__ float ld_sysf(const float* p) {
    return __hip_atomic_load(p, __ATOMIC_RELAXED, __HIP_MEMORY_SCOPE_SYSTEM);
}
__device__ __forceinline__ float2 ld_sysf2(const float* p) {
    union { unsigned long long u; float2 f; } c;
    c.u = __hip_atomic_load((const unsigned long long*)p, __ATOMIC_RELAXED,
                            __HIP_MEMORY_SCOPE_SYSTEM);
    return c.f;
}
__device__ __forceinline__ void st_sysf(float* p, float v) {
    __hip_atomic_store(p, v, __ATOMIC_RELAXED, __HIP_MEMORY_SCOPE_SYSTEM);
}
__device__ __forceinline__ void st_sysf2(float* p, float a, float b) {
    union { unsigned long long u; float2 f; } c;
    c.f = make_float2(a, b);
    __hip_atomic_store((unsigned long long*)p, c.u, __ATOMIC_RELAXED,
                       __HIP_MEMORY_SCOPE_SYSTEM);
}

// 8-float load/store with scope selected by row class (sys = boundary row)
__device__ __forceinline__ void ld8(const float* p, float* v, bool sys) {
    if (sys) {
        #pragma unroll
        for (int h = 0; h < 4; h++) {
            float2 t = ld_sysf2(p + 2*h);
            v[2*h] = t.x; v[2*h+1] = t.y;
        }
    } else {
        float4 a = *(const float4*)p;
        float4 b = *(const float4*)(p + 4);
        v[0]=a.x; v[1]=a.y; v[2]=a.z; v[3]=a.w;
        v[4]=b.x; v[5]=b.y; v[6]=b.z; v[7]=b.w;
    }
}
__device__ __forceinline__ void st8(float* p, const float* v, bool sys) {
    if (sys) {
        st_sysf2(p,     v[0], v[1]);
        st_sysf2(p + 2, v[2], v[3]);
        st_sysf2(p + 4, v[4], v[5]);
        st_sysf2(p + 6, v[6], v[7]);
    } else {
        *(float4*)p       = make_float4(v[0], v[1], v[2], v[3]);
        *(float4*)(p + 4) = make_float4(v[4], v[5], v[6], v[7]);
    }
}

// ---------------- init: y0 (px-major) = concat(x, zeros); zero sync state ----------------
__global__ __launch_bounds__(256)
void k_init(const float* __restrict__ x, float* __restrict__ y,
            int* __restrict__ flags, unsigned* __restrict__ cnt)
{
    int idx = blockIdx.x*256 + threadIdx.x;           // < NS
    int b = idx >> 13, px = (idx >> 3) & 1023, c = idx & 7;
    y[idx] = (c < 3) ? x[(size_t)(b*3 + c)*1024 + px] : 0.0f;
    if (idx < 512) flags[idx] = 0;
    if (idx == 600) *cnt = 0u;
}

// ---------------- prepack w2 into fp16 32x32x16 B-frag order + t-channel table ----------------
// flat frag index: ((tap*4 + ks)*2 + nt)*512 + lane*8 + j
// lane: oc = nt*32 + (lane&31), k: ic = ks*16 + (lane>>5)*8 + j
__global__ __launch_bounds__(256)
void k_prepack(const float* __restrict__ w2, _Float16* __restrict__ w2p,
               float* __restrict__ tsum)
{
    int gid = blockIdx.x*256 + threadIdx.x;
    if (gid < 36864) {
        int j    = gid & 7;
        int lane = (gid >> 3) & 63;
        int nt   = (gid >> 9) & 1;
        int ks   = (gid >> 10) & 3;
        int tap  = gid >> 12;            // 0..8
        int oc = nt*32 + (lane & 31);
        int ic = ks*16 + (lane >> 5)*8 + j;
        w2p[gid] = (_Float16)w2[oc*585 + (1 + ic)*9 + tap];
    }
    if (gid < 576) {
        int oc = gid & 63, combo = gid >> 6;       // 0..8
        int rcase = combo / 3, ccase = combo % 3;
        float s = 0.0f;
        for (int kh = 0; kh < 3; kh++) {
            if ((rcase == 1 && kh == 0) || (rcase == 2 && kh == 2)) continue;
            for (int kw = 0; kw < 3; kw++) {
                if ((ccase == 1 && kw == 0) || (ccase == 2 && kw == 2)) continue;
                s += w2[oc*585 + kh*3 + kw];
            }
        }
        tsum[gid] = s;
    }
}

// ---------------- the whole ODE solve: one co-resident kernel ----------------
// conv2: single-pass fp16 32x32x16 MFMA (3x fewer matrix-pipe cycles than the
// split-bf16 3-pass). Activations stored fp16 in LDS (128 B used of 272-B px
// stride, layout/banking identical to the verified R9 kernel). t-channel exact.
__global__ void __launch_bounds__(256, 2)
k_ode(const float* __restrict__ w1, const float* __restrict__ b1,
      const float* __restrict__ b2, const float* __restrict__ w3,
      const float* __restrict__ b3, const _Float16* __restrict__ w2p,
      const float* __restrict__ tsumg, const float* __restrict__ wl,
      const float* __restrict__ bl, float* __restrict__ ybuf,
      float* __restrict__ y5buf, float* __restrict__ kb,
      float* __restrict__ part, int* __restrict__ flags,
      unsigned* __restrict__ cnt, float* __restrict__ out)
{
    __shared__ __align__(16) unsigned char s_pool[55488];
    __shared__ __align__(16) float s_w1t[8][64];
    __shared__ float s_w10[64], s_b1v[64];
    __shared__ __align__(16) float s_w3t[64][8];
    __shared__ float s_w30[8], s_b3v[8];
    __shared__ float s_tsum[576];
    __shared__ float s_b2v[64];
    __shared__ float s_red[256];

    const int tid = threadIdx.x;
    const int nblk = gridDim.x;
    const int lane = tid & 63;
    const int m32 = lane & 31, q2 = lane >> 5;
    const int rp = tid >> 7;          // row-pair of the 4-row tile
    const int np = (tid >> 6) & 1;    // oc-half

    if (tid < 64) {
        s_b1v[tid] = b1[tid];
        s_w10[tid] = w1[tid*9];
        #pragma unroll
        for (int c = 0; c < 8; c++) s_w1t[c][tid] = w1[tid*9 + 1 + c];
        s_b2v[tid] = b2[tid];
        #pragma unroll
        for (int o = 0; o < 8; o++) s_w3t[tid][o] = w3[o*65 + 1 + tid];
        if (tid < 8) { s_w30[tid] = w3[tid*65]; s_b3v[tid] = b3[tid]; }
    }
    for (int i = tid; i < 576; i += 256) s_tsum[i] = tsumg[i];

    float t = 0.0f, dt = 0.1f;
    float* ya = ybuf; float* yb = y5buf;
    float* ka = kb;  float* kg = kb + 6*(size_t)NS;
    unsigned rnd = 0;

    auto rendezvous = [&]() {
        rnd++;
        __syncthreads();
        if (tid == 0) {
            __hip_atomic_fetch_add(cnt, 1u, __ATOMIC_RELAXED, __HIP_MEMORY_SCOPE_SYSTEM);
            unsigned target = (unsigned)nblk * rnd;
            while (__hip_atomic_load(cnt, __ATOMIC_RELAXED,
                                     __HIP_MEMORY_SCOPE_SYSTEM) < target)
                __builtin_amdgcn_s_sleep(2);
        }
        __syncthreads();
    };

    auto eval = [&](const float* src, int nc, const float* cf, float ctv,
                    float* kout, int mode, int gev, float* partp) {
        float dtc = fminf(dt, 1.0f - t);
        float ts  = t + ctv*dtc;

        for (int tile = blockIdx.x; tile < 512; tile += nblk) {
            int b = tile >> 3, rg = tile & 7;

            // 1) zero halo columns (cols 0 & 33, 6 rows, 128 B each); tid0 spins
            if (tid < 96) {
                int px_id = tid >> 3, u = tid & 7;
                int row = px_id >> 1, colh = (px_id & 1) ? 33 : 0;
                *(uint4*)(s_pool + (size_t)(row*34 + colh)*272 + u*16) =
                    make_uint4(0u,0u,0u,0u);
            }
            if (tid == 0 && gev > 1) {
                if (rg > 0)
                    while (__hip_atomic_load(&flags[tile-1], __ATOMIC_RELAXED,
                                             __HIP_MEMORY_SCOPE_SYSTEM) < gev-1)
                        __builtin_amdgcn_s_sleep(1);
                if (rg < 7)
                    while (__hip_atomic_load(&flags[tile+1], __ATOMIC_RELAXED,
                                             __HIP_MEMORY_SCOPE_SYSTEM) < gev-1)
                        __builtin_amdgcn_s_sleep(1);
            }
            __syncthreads();

            // 2) conv1 (z-combine + 1x1 9->64 + relu) -> fp16 into LDS, 6 rows
            if (tid < 192) {
                int lr = tid >> 5, col = tid & 31;
                int r = rg*4 - 1 + lr;
                bool sysrow = (lr < 2) | (lr > 3);   // rows 1,2 of own tile private
                int pxi = lr*34 + col + 1;
                uint4* d = (uint4*)(s_pool + (size_t)pxi*272);
                if ((unsigned)r < 32u) {
                    int px = (r << 5) + col;
                    size_t pb8 = ((size_t)(b << 10) + px) << 3;
                    float s[8] = {0,0,0,0,0,0,0,0};
                    for (int j = 0; j < nc; j++) {
                        const float* kp = (j == 0 ? ka : kb + (size_t)j*NS) + pb8;
                        float a = cf[j];
                        float kv[8];
                        ld8(kp, kv, sysrow);
                        #pragma unroll
                        for (int c = 0; c < 8; c++) s[c] += a*kv[c];
                    }
                    float zz[8];
                    {
                        float sv[8];
                        ld8(src + pb8, sv, sysrow);
                        #pragma unroll
                        for (int c = 0; c < 8; c++) zz[c] = sv[c] + dtc*s[c];
                    }
                    float acc[64];
                    #pragma unroll
                    for (int o = 0; o < 64; o++) acc[o] = fmaf(ts, s_w10[o], s_b1v[o]);
                    #pragma unroll
                    for (int c = 0; c < 8; c++) {
                        float zc = zz[c];
                        const float4* w4 = reinterpret_cast<const float4*>(&s_w1t[c][0]);
                        #pragma unroll
                        for (int qq = 0; qq < 16; qq++) {
                            float4 wq = w4[qq];
                            acc[4*qq+0] = fmaf(wq.x, zc, acc[4*qq+0]);
                            acc[4*qq+1] = fmaf(wq.y, zc, acc[4*qq+1]);
                            acc[4*qq+2] = fmaf(wq.z, zc, acc[4*qq+2]);
                            acc[4*qq+3] = fmaf(wq.w, zc, acc[4*qq+3]);
                        }
                    }
                    unsigned hbuf[32];
                    #pragma unroll
                    for (int i = 0; i < 32; i++) {
                        union { _Float16 h[2]; unsigned u; } p;
                        p.h[0] = (_Float16)fmaxf(acc[2*i],   0.0f);
                        p.h[1] = (_Float16)fmaxf(acc[2*i+1], 0.0f);
                        hbuf[i] = p.u;
                    }
                    const uint4* hv = (const uint4*)hbuf;
                    #pragma unroll
                    for (int i = 0; i < 8; i++) d[i] = hv[i];
                } else {
                    uint4 z4 = make_uint4(0u,0u,0u,0u);
                    #pragma unroll
                    for (int i = 0; i < 8; i++) d[i] = z4;
                }
            }
            __syncthreads();

            // 3) conv2: 3x3 65->64 single-pass fp16 via 32x32x16 MFMA
            f32x16 acc2[2];   // [ri]
            acc2[0] = (f32x16)(0.0f);
            acc2[1] = (f32x16)(0.0f);

            for (int cc = 0; cc < 2; cc++) {
                #pragma unroll 1
                for (int kh = 0; kh < 3; kh++) {
                    #pragma unroll
                    for (int kw = 0; kw < 3; kw++) {
                        int tap = kh*3 + kw;
                        #pragma unroll
                        for (int s = 0; s < 2; s++) {
                            int ks = cc*2 + s;
                            hfrag8 bh = *(const hfrag8*)
                                (w2p + (size_t)((tap*4 + ks)*2 + np)*512 + lane*8);
                            int aoff = ks*32 + q2*16;
                            #pragma unroll
                            for (int ri = 0; ri < 2; ri++) {
                                int lr = rp*2 + ri + kh;
                                hfrag8 ah = *(const hfrag8*)(s_pool
                                    + (size_t)(lr*34 + m32 + kw)*272 + aoff);
                                acc2[ri] = __builtin_amdgcn_mfma_f32_32x32x16_f16(
                                    ah, bh, acc2[ri], 0, 0, 0);
                            }
                        }
                    }
                }
            }
            __syncthreads();   // before h2 overlay on pool

            // 4) epilogue: t-channel + bias + relu -> LDS h2, oc-major stride 129
            // C/D: oc = lane&31 (col), px = (reg&3)+8*(reg>>2)+4*q2 (row)
            {
                float* s_h2 = (float*)s_pool;
                int oc = np*32 + m32;
                float tb = s_b2v[oc];
                #pragma unroll
                for (int ri = 0; ri < 2; ri++) {
                    int lrow = rp*2 + ri;
                    int r_out = rg*4 + lrow;
                    int rcase = (r_out == 0) ? 1 : ((r_out == 31) ? 2 : 0);
                    #pragma unroll
                    for (int reg = 0; reg < 16; reg++) {
                        int cpos = (reg & 3) + 8*(reg >> 2) + 4*q2;
                        int ccase = (cpos == 0) ? 1 : ((cpos == 31) ? 2 : 0);
                        float tsv = s_tsum[(rcase*3 + ccase)*64 + oc];
                        s_h2[oc*129 + lrow*32 + cpos] =
                            fmaxf(acc2[ri][reg] + ts*tsv + tb, 0.0f);
                    }
                }
            }
            __syncthreads();

            // 5) conv3 (1x1 65->8) + mode epilogues (scope per row class)
            if (tid < 128) {
                const float* s_h2 = (const float*)s_pool;
                float a3[8];
                #pragma unroll
                for (int o = 0; o < 8; o++) a3[o] = fmaf(ts, s_w30[o], s_b3v[o]);
                #pragma unroll 8
                for (int c = 0; c < 64; c++) {
                    float xv = s_h2[c*129 + tid];
                    const float4* w4 = (const float4*)&s_w3t[c][0];
                    float4 wA = w4[0], wB = w4[1];
                    a3[0] = fmaf(wA.x, xv, a3[0]);
                    a3[1] = fmaf(wA.y, xv, a3[1]);
                    a3[2] = fmaf(wA.z, xv, a3[2]);
                    a3[3] = fmaf(wA.w, xv, a3[3]);
                    a3[4] = fmaf(wB.x, xv, a3[4]);
                    a3[5] = fmaf(wB.y, xv, a3[5]);
                    a3[6] = fmaf(wB.z, xv, a3[6]);
                    a3[7] = fmaf(wB.w, xv, a3[7]);
                }
                int lrow = tid >> 5;
                bool sysrow = (lrow == 0) | (lrow == 3);
                int px = rg*128 + tid;
                size_t pb8 = ((size_t)(b << 10) + px) << 3;
                st8(kout + pb8, a3, sysrow);
                if (mode == 1) {
                    float kv1[8], kv3[8], kv4[8], kv5[8], yv[8], r8[8];
                    ld8(ka + pb8, kv1, sysrow);
                    ld8(kb + 2*(size_t)NS + pb8, kv3, sysrow);
                    ld8(kb + 3*(size_t)NS + pb8, kv4, sysrow);
                    ld8(kb + 4*(size_t)NS + pb8, kv5, sysrow);
                    ld8(ya + pb8, yv, sysrow);
                    #pragma unroll
                    for (int c = 0; c < 8; c++)
                        r8[c] = yv[c] + dtc*(B1c*kv1[c] + B3c*kv3[c] + B4c*kv4[c]
                                             + B5c*kv5[c] + B6c*a3[c]);
                    st8(yb + pb8, r8, sysrow);
                } else if (mode == 2) {
                    float kv1[8], kv3[8], kv4[8], kv5[8], kv6[8], yv[8], y5v[8];
                    ld8(ka + pb8, kv1, sysrow);
                    ld8(kb + 2*(size_t)NS + pb8, kv3, sysrow);
                    ld8(kb + 3*(size_t)NS + pb8, kv4, sysrow);
                    ld8(kb + 4*(size_t)NS + pb8, kv5, sysrow);
                    ld8(kb + 5*(size_t)NS + pb8, kv6, sysrow);
                    ld8(ya + pb8, yv, sysrow);
                    ld8(yb + pb8, y5v, sysrow);
                    float ls = 0.0f;
                    #pragma unroll
                    for (int c = 0; c < 8; c++) {
                        float e = dtc*(E1c*kv1[c] + E3c*kv3[c] + E4c*kv4[c]
                                       + E5c*kv5[c] + E6c*kv6[c] + E7c*a3[c]);
                        float tol = ATOL + RTOL*fmaxf(fabsf(yv[c]), fabsf(y5v[c]));
                        float rr = e / tol;
                        ls += rr*rr;
                    }
                    s_red[tid] = ls;
                }
            }
            if (mode == 2) {
                if (tid >= 128) s_red[tid] = 0.0f;
                __syncthreads();
                for (int sft = 128; sft > 0; sft >>= 1) {
                    if (tid < sft) s_red[tid] += s_red[tid + sft];
                    __syncthreads();
                }
                if (tid == 0) st_sysf(&partp[tile], s_red[0]);
            }
            // release: syncthreads drains vmcnt (sys stores at L3), then flag
            __syncthreads();
            if (tid == 0)
                __hip_atomic_store(&flags[tile], gev, __ATOMIC_RELAXED,
                                   __HIP_MEMORY_SCOPE_SYSTEM);
        }
    };

    int gev = 1;
    eval(ya, 0, g_cf[5], 0.0f, ka, 0, gev, part);   // k1 = f(t0, y0)
    gev++;

    for (int st = 0; st < 24; st++) {
        if (t >= 1.0f - 1e-7f) break;
        float* partp = part + (size_t)(st & 1)*512;
        for (int e = 0; e < 6; e++) {
            int nc = (e < 5) ? e + 1 : 0;
            const float* src = (e == 5) ? yb : ya;
            float* kout = (e < 5) ? kb + (size_t)(e + 1)*NS : kg;
            int mode = (e == 4) ? 1 : ((e == 5) ? 2 : 0);
            eval(src, nc, g_cf[e], g_ct[e], kout, mode, gev, partp);
            gev++;
        }
        rendezvous();   // all partials (sys) visible
        float v = ld_sysf(&partp[tid]) + ld_sysf(&partp[tid + 256]);
        s_red[tid] = v;
        __syncthreads();
        for (int sft = 128; sft > 0; sft >>= 1) {
            if (tid < sft) s_red[tid] += s_red[tid + sft];
            __syncthreads();
        }
        float red0 = s_red[0];
        __syncthreads();
        float err_norm = sqrtf(red0 / (float)NS);
        float dtc = fminf(dt, 1.0f - t);
        bool adv = (err_norm <= 1.0f);
        if (adv) {
            t = t + dtc;
            float* tmp = ya; ya = yb; yb = tmp;   // y <- y5
            tmp = ka; ka = kg; kg = tmp;          // k1 <- k7 (FSAL)
        }
        float safe = fmaxf(err_norm, 1e-10f);
        float factor = fminf(fmaxf(0.9f*powf(safe, -0.2f), 0.2f), 10.0f);
        dt = dtc*factor;
    }

    // flush private interior rows of final y to L3, then rendezvous
    for (int tile = blockIdx.x; tile < 512; tile += nblk) {
        int b = tile >> 3, rg = tile & 7;
        if (tid < 128) {
            int lrow = tid >> 5;
            if (lrow == 1 || lrow == 2) {
                int px = rg*128 + tid;
                float* yp = ya + (((size_t)(b << 10) + px) << 3);
                float4 v0 = *(const float4*)yp;
                float4 v1 = *(const float4*)(yp + 4);
                st_sysf2(yp,     v0.x, v0.y);
                st_sysf2(yp + 2, v0.z, v0.w);
                st_sysf2(yp + 4, v1.x, v1.y);
                st_sysf2(yp + 6, v1.z, v1.w);
            }
        }
    }
    rendezvous();

    // final linear head: y is px-major [b][px][8]; wl flat index = c*1024+px
    for (int bh = blockIdx.x; bh < 64; bh += nblk) {
        float* s_hred = (float*)s_pool;   // 10*256 floats overlay
        float acc[10];
        #pragma unroll
        for (int m = 0; m < 10; m++) acc[m] = 0.0f;
        for (int px = tid; px < 1024; px += 256) {
            const float* yp = ya + (((size_t)(bh << 10) + px) << 3);
            float yv[8];
            #pragma unroll
            for (int h = 0; h < 4; h++) {
                float2 v = ld_sysf2(yp + 2*h);
                yv[2*h] = v.x; yv[2*h+1] = v.y;
            }
            #pragma unroll
            for (int c = 0; c < 8; c++) {
                float v = yv[c];
                #pragma unroll
                for (int m = 0; m < 10; m++)
                    acc[m] = fmaf(v, wl[(size_t)m*8192 + (c << 10) + px], acc[m]);
            }
        }
        #pragma unroll
        for (int m = 0; m < 10; m++) s_hred[m*256 + tid] = acc[m];
        __syncthreads();
        for (int sft = 128; sft > 0; sft >>= 1) {
            if (tid < sft) {
                #pragma unroll
                for (int m = 0; m < 10; m++)
                    s_hred[m*256 + tid] += s_hred[m*256 + tid + sft];
            }
            __syncthreads();
        }
        if (tid < 10) out[bh*10 + tid] = s_hred[tid*256] + bl[tid];
        __syncthreads();
    }
}

// ---------------- host ----------------
extern "C" void kernel_launch(void* const* d_in, const int* in_sizes, int n_in,
                              void* d_out, int out_size, void* d_ws, size_t ws_size,
                              hipStream_t stream)
{
    const float* x  = (const float*)d_in[0];
    const float* w1 = (const float*)d_in[1];
    const float* b1 = (const float*)d_in[2];
    const float* w2 = (const float*)d_in[3];
    const float* b2 = (const float*)d_in[4];
    const float* w3 = (const float*)d_in[5];
    const float* b3 = (const float*)d_in[6];
    const float* wl = (const float*)d_in[7];
    const float* bl = (const float*)d_in[8];
    float* out = (float*)d_out;

    float* F = (float*)d_ws;
    float* part = F + OFF_PART;
    int*   flags = (int*)(F + OFF_FLAG);
    unsigned* cnt = (unsigned*)(F + OFF_CNT);
    float* tsum = F + OFF_TSUM;
    _Float16* w2p = (_Float16*)(F + OFF_W2P);
    float* y    = F + OFF_Y;
    float* y5   = F + OFF_Y5;
    float* kbp  = F + OFF_K;

    k_init<<<NS/256, 256, 0, stream>>>(x, y, flags, cnt);
    k_prepack<<<144, 256, 0, stream>>>(w2, w2p, tsum);

    // plain launch; grid capped at guaranteed co-resident capacity
    int maxb = 0;
    if (hipOccupancyMaxActiveBlocksPerMultiprocessor(&maxb,
            reinterpret_cast<const void*>(k_ode), 256, 0) != hipSuccess || maxb < 1)
        maxb = 1;
    int cus = 256;
    {
        int dev = 0;
        hipGetDevice(&dev);
        hipDeviceProp_t prop;
        if (hipGetDeviceProperties(&prop, dev) == hipSuccess && prop.multiProcessorCount > 0)
            cus = prop.multiProcessorCount;
    }
    long cap = (long)maxb * (long)cus;
    int gridn = (int)((cap < 512) ? cap : 512);
    if (gridn < 16) gridn = 16;

    k_ode<<<gridn, 256, 0, stream>>>(w1, b1, b2, w3, b3, w2p, tsum, wl, bl,
                                     y, y5, kbp, part, flags, cnt, out);
}